// Round 10
// baseline (190.084 us; speedup 1.0000x reference)
//
#include <hip/hip_runtime.h>

#define HH 8
#define TT 4096
#define DD 128
#define NKT 128              // 32-key tiles per head
#define NEG_BIG (-3.0e38f)
#define DEFER_THR 8.0f       // defer-max threshold: P bounded by e^8

// ws (shorts): Khi[8.4MB] | Klo[8.4MB] | Vt[8.4MB]
#define HEAD_FRAG_SHORTS ((size_t)NKT * 8 * 512)

typedef __attribute__((ext_vector_type(8)))  short short8;
typedef __attribute__((ext_vector_type(16))) float float16;

__device__ __forceinline__ short bf16_rne(float x) {
    unsigned u = __float_as_uint(x);
    return (short)((u + 0x7fffu + ((u >> 16) & 1u)) >> 16);
}
__device__ __forceinline__ float bf16_f(short s) {
    return __uint_as_float(((unsigned)(unsigned short)s) << 16);
}

// ---------------- prep: fp32 K,V -> bf16 hi/lo fragments (verified, unchanged) ----------------
__global__ __launch_bounds__(256) void prep_kernel(
    const float* __restrict__ k, const float* __restrict__ v,
    short* __restrict__ khi, short* __restrict__ klo, short* __restrict__ vt)
{
    const int h = blockIdx.x, kt = blockIdx.y, t = threadIdx.x;
    __shared__ float Vs[32][132];

    #pragma unroll
    for (int it = 0; it < 4; ++it) {               // stage V tile 32 keys x 128 dims
        const int f = t + it * 256, j = f >> 5, c = f & 31;
        *(float4*)&Vs[j][c * 4] =
            *(const float4*)(v + ((size_t)(h * TT + kt * 32 + j)) * DD + c * 4);
    }
    // K fragments: B[n=key m][k-dim = ks*16 + hf*8 + e]
    #pragma unroll
    for (int it = 0; it < 2; ++it) {
        const int idx = t + it * 256;
        const int ks = idx >> 6, ln = idx & 63, m = ln & 31, hf = ln >> 5;
        const float* src = k + ((size_t)(h * TT + kt * 32 + m)) * DD + ks * 16 + hf * 8;
        const float4 a = *(const float4*)src;
        const float4 b = *(const float4*)(src + 4);
        const float f8[8] = {a.x, a.y, a.z, a.w, b.x, b.y, b.z, b.w};
        short8 hi8, lo8;
        #pragma unroll
        for (int e = 0; e < 8; ++e) {
            const short hi_ = bf16_rne(f8[e]);
            hi8[e] = hi_;
            lo8[e] = bf16_rne(f8[e] - bf16_f(hi_));
        }
        const size_t off = ((size_t)((h * NKT + kt) * 8 + ks)) * 512 + ln * 8;
        *(short8*)(khi + off) = hi8;
        *(short8*)(klo + off) = lo8;
    }
    __syncthreads();
    // V fragments: B[n=dim nt*32+m][k-key = ks2*16 + hf*8 + e]
    #pragma unroll
    for (int it = 0; it < 2; ++it) {
        const int idx = t + it * 256;
        const int nt = idx >> 7, ks2 = (idx >> 6) & 1, ln = idx & 63;
        const int m = ln & 31, hf = ln >> 5, n = nt * 32 + m;
        short8 o;
        #pragma unroll
        for (int e = 0; e < 8; ++e)
            o[e] = bf16_rne(Vs[ks2 * 16 + hf * 8 + e][n]);
        *(short8*)(vt + ((size_t)(((h * NKT + kt) * 4 + nt) * 2 + ks2)) * 512 + ln * 8) = o;
    }
}

// ------- attention: 4-wave split-K, Q in LDS, dual-chain SWAPPED QK, defer-max,
//         in-register P (no LDS round-trip) -------
// A/B fragment layouts are symmetric on CDNA (matrix-idx = lane&31, k = 8hf+e),
// so mfma(K,Q) transposes acc for free: lane = q-row m, reg r = key
// (r&3)+8(r>>2)+4hf. P is then lane-local: PV's A-frag is built in registers
// via 8 cvt_pk_bf16 + 8 shfl_xor(32) (partner-half exchange) + hf-selects,
// deleting the 16 ds_write + 8 ds_read P round-trip (R9 showed extra ILP is
// useless; only serial-work REMOVAL has moved time: R6 -12us, R8 -9us).
// ls collapses to one scalar/lane; epilogue reduce = one shfl_xor(32).
// No setprio (R5), no K reg-prefetch (R7), no 2-tile pipeline (R9): all tested.
__global__ __launch_bounds__(256, 2) void attn_kernel(
    const float* __restrict__ q,
    const short* __restrict__ khi, const short* __restrict__ klo,
    const short* __restrict__ vt, float* __restrict__ out)
{
    const int h = blockIdx.x;                          // head -> XCD L2 pinning
    const int g = (int)(gridDim.y - 1) - (int)blockIdx.y;  // big row-tiles first
    const int growb = g * 32;
    const int t = threadIdx.x, w = t >> 6, ln = t & 63, m = ln & 31, hf = ln >> 5;

    // qf lifetime: staging + kt loop. oc lifetime: combine (after barrier). Union ok.
    __shared__ union {
        short qf[2][16][32][8];                        // 16 KB [hi/lo][ks*2+hf][m][e]
        float oc[4][32][36];                           // 18.4 KB combine chunks
    } U;
    __shared__ float Lw[4][32];
    __shared__ float Mw[4];

    const short* khiH = khi + (size_t)h * HEAD_FRAG_SHORTS;
    const short* kloH = klo + (size_t)h * HEAD_FRAG_SHORTS;
    const short* vtH  = vt  + (size_t)h * HEAD_FRAG_SHORTS;

    // ---- stage Q (32 rows) as bf16 hi/lo A-fragments into LDS (once per block)
    #pragma unroll
    for (int it = 0; it < 2; ++it) {
        const int idx = t + it * 256;                  // 512 fragments: ks*2*32 + hf*32 + m
        const int ks = idx >> 6, l2 = idx & 63, mm = l2 & 31, hh = l2 >> 5;
        const float* src = q + ((size_t)(h * TT + growb + mm)) * DD + ks * 16 + hh * 8;
        const float4 a = *(const float4*)src;
        const float4 b = *(const float4*)(src + 4);
        const float f8[8] = {a.x, a.y, a.z, a.w, b.x, b.y, b.z, b.w};
        short8 hi8, lo8;
        #pragma unroll
        for (int e = 0; e < 8; ++e) {
            const short hi_ = bf16_rne(f8[e]);
            hi8[e] = hi_;
            lo8[e] = bf16_rne(f8[e] - bf16_f(hi_));
        }
        *(short8*)&U.qf[0][ks * 2 + hh][mm][0] = hi8;
        *(short8*)&U.qf[1][ks * 2 + hh][mm][0] = lo8;
    }
    __syncthreads();

    float16 Oa[4];
    #pragma unroll
    for (int nt = 0; nt < 4; ++nt)
        #pragma unroll
        for (int r = 0; r < 16; ++r) Oa[nt][r] = 0.f;
    float ls = 0.f;                                    // per-lane = per-q-row partial sum
    float mrun = NEG_BIG;                              // wave-uniform running max

    // per-lane Q base byte offset; blinded each iteration so the 16 LDS frag
    // reads are NOT hoisted into 64 registers across the loop
    int qoff = (hf * 32 + m) * 16;

    #pragma unroll 1
    for (int kt = w; kt <= g; kt += 4) {               // split-K: wave w owns kt≡w (mod 4)
        asm volatile("" : "+v"(qoff));                 // defeat loop-invariance
        const char* qb0 = (const char*)&U.qf[0][0][0][0] + qoff;

        // ---- QK^T SWAPPED (A=K, B=Q): 8 k-steps x 3 split-MFMAs, TWO chains ----
        // acc layout: lane = q-row m, reg r = key (r&3)+8*(r>>2)+4*hf
        float16 accA, accB;
        #pragma unroll
        for (int r = 0; r < 16; ++r) { accA[r] = 0.f; accB[r] = 0.f; }
        #pragma unroll
        for (int ks = 0; ks < 8; ks += 2) {
            union { int4 i4; short8 s; } bhA, blA, qhA, qlA, bhB, blB, qhB, qlB;
            const size_t foA = ((size_t)(kt * 8 + ks)) * 512 + ln * 8;
            const size_t foB = ((size_t)(kt * 8 + ks + 1)) * 512 + ln * 8;
            bhA.i4 = *(const int4*)(khiH + foA);
            bhB.i4 = *(const int4*)(khiH + foB);
            blA.i4 = *(const int4*)(kloH + foA);
            blB.i4 = *(const int4*)(kloH + foB);
            qhA.i4 = *(const int4*)(qb0 + ks * 1024);
            qhB.i4 = *(const int4*)(qb0 + (ks + 1) * 1024);
            qlA.i4 = *(const int4*)(qb0 + 8192 + ks * 1024);
            qlB.i4 = *(const int4*)(qb0 + 8192 + (ks + 1) * 1024);
            accA = __builtin_amdgcn_mfma_f32_32x32x16_bf16(bhA.s, qhA.s, accA, 0, 0, 0);
            accB = __builtin_amdgcn_mfma_f32_32x32x16_bf16(bhB.s, qhB.s, accB, 0, 0, 0);
            accA = __builtin_amdgcn_mfma_f32_32x32x16_bf16(bhA.s, qlA.s, accA, 0, 0, 0);
            accB = __builtin_amdgcn_mfma_f32_32x32x16_bf16(bhB.s, qlB.s, accB, 0, 0, 0);
            accA = __builtin_amdgcn_mfma_f32_32x32x16_bf16(blA.s, qhA.s, accA, 0, 0, 0);
            accB = __builtin_amdgcn_mfma_f32_32x32x16_bf16(blB.s, qhB.s, accB, 0, 0, 0);
        }
        float16 acc;
        #pragma unroll
        for (int r = 0; r < 16; ++r) acc[r] = accA[r] + accB[r];

        // V fragment preload: issued here so softmax hides the L2 latency
        int4 vb[8];
        #pragma unroll
        for (int u = 0; u < 8; ++u)
            vb[u] = *(const int4*)(vtH + ((size_t)(kt * 8 + u)) * 512 + ln * 8);

        // causal mask (diagonal tile): mask keys > q-row (swapped layout)
        if (kt == g) {
            #pragma unroll
            for (int r = 0; r < 16; ++r)
                if (4 * hf + (r & 3) + 8 * (r >> 2) > m) acc[r] = NEG_BIG;
        }

        // ---- defer-max online softmax (wave-uniform mrun, verbatim trigger) ----
        float tm = acc[0];
        #pragma unroll
        for (int r = 1; r < 16; ++r) tm = fmaxf(tm, acc[r]);
        if (__any(tm > mrun + DEFER_THR)) {            // wave-uniform trigger
            float tw = tm;
            #pragma unroll
            for (int off = 32; off > 0; off >>= 1)
                tw = fmaxf(tw, __shfl_xor(tw, off, 64));
            const float mnew  = fmaxf(mrun, tw);
            const float alpha = __expf(mrun - mnew);   // first tile: 0
            #pragma unroll
            for (int r = 0; r < 16; ++r) {
                Oa[0][r] *= alpha; Oa[1][r] *= alpha;
                Oa[2][r] *= alpha; Oa[3][r] *= alpha;
            }
            ls *= alpha;
            mrun = mnew;
        }
        float p[16];
        #pragma unroll
        for (int r = 0; r < 16; ++r) {
            p[r] = __expf(acc[r] - mrun);              // bounded by e^8; masked -> 0
            ls += p[r];
        }

        // ---- in-register P pack (replaces Pl LDS round-trip) ----
        // lane(m,hf) owns keys {4hf+(r&3)+8(r>>2)}; partner lane (m,hf^1) holds
        // the missing quads -> one shfl_xor(32) per packed u32.
        // A-frag for ks2: keys ks2*16 + hf*8 + {0..7}.
        union { unsigned u[4]; short8 s; } paf[2];
        #pragma unroll
        for (int gp = 0; gp < 2; ++gp) {               // gp == ks2
            unsigned a0, a1, a2, a3;
            asm("v_cvt_pk_bf16_f32 %0, %1, %2" : "=v"(a0) : "v"(p[gp*8+0]), "v"(p[gp*8+1]));
            asm("v_cvt_pk_bf16_f32 %0, %1, %2" : "=v"(a1) : "v"(p[gp*8+2]), "v"(p[gp*8+3]));
            asm("v_cvt_pk_bf16_f32 %0, %1, %2" : "=v"(a2) : "v"(p[gp*8+4]), "v"(p[gp*8+5]));
            asm("v_cvt_pk_bf16_f32 %0, %1, %2" : "=v"(a3) : "v"(p[gp*8+6]), "v"(p[gp*8+7]));
            const unsigned b0 = (unsigned)__shfl_xor((int)a0, 32, 64);
            const unsigned b1 = (unsigned)__shfl_xor((int)a1, 32, 64);
            const unsigned b2 = (unsigned)__shfl_xor((int)a2, 32, 64);
            const unsigned b3 = (unsigned)__shfl_xor((int)a3, 32, 64);
            // hf=0 lane: keys 8gp*?+0..7  = [a0 a1 b0 b1]   (own quad 0-3, partner 4-7)
            // hf=1 lane: keys ..8..15     = [b2 b3 a2 a3]   (partner 8-11, own 12-15)
            paf[gp].u[0] = hf ? b2 : a0;
            paf[gp].u[1] = hf ? b3 : a1;
            paf[gp].u[2] = hf ? a2 : b0;
            paf[gp].u[3] = hf ? a3 : b1;
        }

        // ---- PV (A = in-register P, B = V frags; layout identical to before) ----
        #pragma unroll
        for (int ks2 = 0; ks2 < 2; ++ks2) {
            #pragma unroll
            for (int nt = 0; nt < 4; ++nt) {
                union { int4 i4; short8 s; } uv;
                uv.i4 = vb[nt * 2 + ks2];
                Oa[nt] = __builtin_amdgcn_mfma_f32_32x32x16_bf16(paf[ks2].s, uv.s, Oa[nt], 0, 0, 0);
            }
        }
    }

    // ---- epilogue l: combine the two hf halves of each q-row (one shuffle) ----
    ls += __shfl_xor(ls, 32, 64);
    Lw[w][m] = ls;                                     // both halves write same value
    if (ln == 0) Mw[w] = mrun;                         // idle wave (w>g): NEG_BIG
    __syncthreads();                                   // qf dead from here; oc alive

    // ---- flash-decoding combine across the 4 split-K waves, 32-dim chunks ----
    const int crow = t >> 3, c0 = (t & 7) * 4;
    const float M = fmaxf(fmaxf(Mw[0], Mw[1]), fmaxf(Mw[2], Mw[3]));
    float ee[4];
    #pragma unroll
    for (int u = 0; u < 4; ++u) ee[u] = __expf(Mw[u] - M);  // idle wave -> 0
    const float L = ee[0] * Lw[0][crow] + ee[1] * Lw[1][crow]
                  + ee[2] * Lw[2][crow] + ee[3] * Lw[3][crow];
    const float inv = 1.f / L;
    float* op = out + ((size_t)(h * TT + growb + crow)) * DD;

    #pragma unroll
    for (int nt = 0; nt < 4; ++nt) {
        __syncthreads();                               // OC free for this chunk
        #pragma unroll
        for (int r = 0; r < 16; ++r)
            U.oc[w][4 * hf + (r & 3) + 8 * (r >> 2)][m] = Oa[nt][r];
        __syncthreads();                               // chunk visible
        float4 s4 = {0.f, 0.f, 0.f, 0.f};
        #pragma unroll
        for (int u = 0; u < 4; ++u) {
            const float4 ov = *(const float4*)&U.oc[u][crow][c0];
            s4.x += ee[u] * ov.x; s4.y += ee[u] * ov.y;
            s4.z += ee[u] * ov.z; s4.w += ee[u] * ov.w;
        }
        s4.x *= inv; s4.y *= inv; s4.z *= inv; s4.w *= inv;
        *(float4*)(op + nt * 32 + c0) = s4;
    }
}

extern "C" void kernel_launch(void* const* d_in, const int* in_sizes, int n_in,
                              void* d_out, int out_size, void* d_ws, size_t ws_size,
                              hipStream_t stream) {
    const float* q = (const float*)d_in[0];
    const float* k = (const float*)d_in[1];
    const float* v = (const float*)d_in[2];
    float* out = (float*)d_out;

    short* khi = (short*)d_ws;
    short* klo = khi + (size_t)HH * HEAD_FRAG_SHORTS;
    short* vt  = klo + (size_t)HH * HEAD_FRAG_SHORTS;

    prep_kernel<<<dim3(HH, NKT), dim3(256), 0, stream>>>(k, v, khi, klo, vt);
    attn_kernel<<<dim3(HH, NKT), dim3(256), 0, stream>>>(q, khi, klo, vt, out);
}

// Round 13
// 182.566 us; speedup vs baseline: 1.0412x; 1.0412x over previous
//
#include <hip/hip_runtime.h>

#define HH 8
#define TT 4096
#define DD 128
#define NKT 128              // 32-key tiles per head
#define PS 36                // P row stride in shorts (72 B rows)
#define NEG_BIG (-3.0e38f)
#define DEFER_THR 8.0f       // defer-max threshold: P bounded by e^8

// ws (shorts): Khi[8.4MB] | Klo[8.4MB] | Vt[8.4MB]
#define HEAD_FRAG_SHORTS ((size_t)NKT * 8 * 512)

typedef __attribute__((ext_vector_type(8)))  short short8;
typedef __attribute__((ext_vector_type(16))) float float16;

__device__ __forceinline__ short bf16_rne(float x) {
    unsigned u = __float_as_uint(x);
    return (short)((u + 0x7fffu + ((u >> 16) & 1u)) >> 16);
}
__device__ __forceinline__ float bf16_f(short s) {
    return __uint_as_float(((unsigned)(unsigned short)s) << 16);
}

// ---------------- prep v2: fp32 K,V -> bf16 hi/lo fragments ----------------
// Same output bytes as v1; access pattern fixed. v1's K-fragment phase read
// global memory at 512B lane stride (32B/lane scatter). v2 stages BOTH tiles
// into LDS with coalesced float4 row loads (two 512B segments per wave),
// then converts K frags from LDS as contiguous reads. Probe: if the constant
// ~76us total-minus-attn residual is prep, this collapses it; if it's fixed
// harness overhead, total is unchanged and prep is exonerated.
__global__ __launch_bounds__(256) void prep_kernel(
    const float* __restrict__ k, const float* __restrict__ v,
    short* __restrict__ khi, short* __restrict__ klo, short* __restrict__ vt)
{
    const int h = blockIdx.x, kt = blockIdx.y, t = threadIdx.x;
    __shared__ float Ks[32][132];
    __shared__ float Vs[32][132];

    #pragma unroll
    for (int it = 0; it < 4; ++it) {               // stage K and V tiles, coalesced
        const int f = t + it * 256, j = f >> 5, c = f & 31;
        const size_t rowoff = ((size_t)(h * TT + kt * 32 + j)) * DD + c * 4;
        *(float4*)&Ks[j][c * 4] = *(const float4*)(k + rowoff);
        *(float4*)&Vs[j][c * 4] = *(const float4*)(v + rowoff);
    }
    __syncthreads();

    // K fragments: B[n=key m][k-dim = ks*16 + hf*8 + e], read contiguous from LDS
    #pragma unroll
    for (int it = 0; it < 2; ++it) {
        const int idx = t + it * 256;
        const int ks = idx >> 6, ln = idx & 63, m = ln & 31, hf = ln >> 5;
        const float4 a = *(const float4*)&Ks[m][ks * 16 + hf * 8];
        const float4 b = *(const float4*)&Ks[m][ks * 16 + hf * 8 + 4];
        const float f8[8] = {a.x, a.y, a.z, a.w, b.x, b.y, b.z, b.w};
        short8 hi8, lo8;
        #pragma unroll
        for (int e = 0; e < 8; ++e) {
            const short hi_ = bf16_rne(f8[e]);
            hi8[e] = hi_;
            lo8[e] = bf16_rne(f8[e] - bf16_f(hi_));
        }
        const size_t off = ((size_t)((h * NKT + kt) * 8 + ks)) * 512 + ln * 8;
        *(short8*)(khi + off) = hi8;
        *(short8*)(klo + off) = lo8;
    }

    // V fragments: B[n=dim nt*32+m][k-key = ks2*16 + hf*8 + e] (unchanged math)
    #pragma unroll
    for (int it = 0; it < 2; ++it) {
        const int idx = t + it * 256;
        const int nt = idx >> 7, ks2 = (idx >> 6) & 1, ln = idx & 63;
        const int m = ln & 31, hf = ln >> 5, n = nt * 32 + m;
        short8 o;
        #pragma unroll
        for (int e = 0; e < 8; ++e)
            o[e] = bf16_rne(Vs[ks2 * 16 + hf * 8 + e][n]);
        *(short8*)(vt + ((size_t)(((h * NKT + kt) * 4 + nt) * 2 + ks2)) * 512 + ln * 8) = o;
    }
}

// ------- attention: R8 verbatim (103.6µs verified) — 4-wave split-K, Q in LDS,
//         dual-chain 3-term QK, defer-max softmax -------
// R12 measured the numerics boundary: dropping Qh*Klo -> absmax 0.109 > 0.101.
// Full 3-term restored; this round's variable is prep only.
__global__ __launch_bounds__(256, 2) void attn_kernel(
    const float* __restrict__ q,
    const short* __restrict__ khi, const short* __restrict__ klo,
    const short* __restrict__ vt, float* __restrict__ out)
{
    const int h = blockIdx.x;                          // head -> XCD L2 pinning
    const int g = (int)(gridDim.y - 1) - (int)blockIdx.y;  // big row-tiles first
    const int growb = g * 32;
    const int t = threadIdx.x, w = t >> 6, ln = t & 63, m = ln & 31, hf = ln >> 5;

    // qf lifetime: staging + kt loop. oc lifetime: combine (after barrier). Union ok.
    __shared__ union {
        short qf[2][16][32][8];                        // 16 KB [hi/lo][ks*2+hf][m][e]
        float oc[4][32][36];                           // 18.4 KB combine chunks
    } U;
    __shared__ short Pl[4][32][PS];                    // wave-private P slabs (9.2 KB)
    __shared__ float Lw[4][32];
    __shared__ float Mw[4];

    const short* khiH = khi + (size_t)h * HEAD_FRAG_SHORTS;
    const short* kloH = klo + (size_t)h * HEAD_FRAG_SHORTS;
    const short* vtH  = vt  + (size_t)h * HEAD_FRAG_SHORTS;

    // ---- stage Q (32 rows) as bf16 hi/lo A-fragments into LDS (once per block)
    #pragma unroll
    for (int it = 0; it < 2; ++it) {
        const int idx = t + it * 256;                  // 512 fragments: ks*2*32 + hf*32 + m
        const int ks = idx >> 6, l2 = idx & 63, mm = l2 & 31, hh = l2 >> 5;
        const float* src = q + ((size_t)(h * TT + growb + mm)) * DD + ks * 16 + hh * 8;
        const float4 a = *(const float4*)src;
        const float4 b = *(const float4*)(src + 4);
        const float f8[8] = {a.x, a.y, a.z, a.w, b.x, b.y, b.z, b.w};
        short8 hi8, lo8;
        #pragma unroll
        for (int e = 0; e < 8; ++e) {
            const short hi_ = bf16_rne(f8[e]);
            hi8[e] = hi_;
            lo8[e] = bf16_rne(f8[e] - bf16_f(hi_));
        }
        *(short8*)&U.qf[0][ks * 2 + hh][mm][0] = hi8;
        *(short8*)&U.qf[1][ks * 2 + hh][mm][0] = lo8;
    }
    __syncthreads();

    float16 Oa[4];
    float ls[16];
    #pragma unroll
    for (int nt = 0; nt < 4; ++nt)
        #pragma unroll
        for (int r = 0; r < 16; ++r) Oa[nt][r] = 0.f;
    #pragma unroll
    for (int r = 0; r < 16; ++r) ls[r] = 0.f;
    float mrun = NEG_BIG;

    // per-lane Q base byte offset; blinded each iteration so the 16 LDS frag
    // reads are NOT hoisted into 64 registers across the loop
    int qoff = (hf * 32 + m) * 16;

    #pragma unroll 1
    for (int kt = w; kt <= g; kt += 4) {               // split-K: wave w owns kt≡w (mod 4)
        asm volatile("" : "+v"(qoff));                 // defeat loop-invariance
        const char* qb0 = (const char*)&U.qf[0][0][0][0] + qoff;

        // ---- QK^T: 8 k-steps x 3 split-MFMAs, TWO independent acc chains ----
        float16 accA, accB;
        #pragma unroll
        for (int r = 0; r < 16; ++r) { accA[r] = 0.f; accB[r] = 0.f; }
        #pragma unroll
        for (int ks = 0; ks < 8; ks += 2) {
            union { int4 i4; short8 s; } bhA, blA, qhA, qlA, bhB, blB, qhB, qlB;
            const size_t foA = ((size_t)(kt * 8 + ks)) * 512 + ln * 8;
            const size_t foB = ((size_t)(kt * 8 + ks + 1)) * 512 + ln * 8;
            bhA.i4 = *(const int4*)(khiH + foA);
            bhB.i4 = *(const int4*)(khiH + foB);
            blA.i4 = *(const int4*)(kloH + foA);
            blB.i4 = *(const int4*)(kloH + foB);
            qhA.i4 = *(const int4*)(qb0 + ks * 1024);
            qhB.i4 = *(const int4*)(qb0 + (ks + 1) * 1024);
            qlA.i4 = *(const int4*)(qb0 + 8192 + ks * 1024);
            qlB.i4 = *(const int4*)(qb0 + 8192 + (ks + 1) * 1024);
            accA = __builtin_amdgcn_mfma_f32_32x32x16_bf16(qhA.s, bhA.s, accA, 0, 0, 0);
            accB = __builtin_amdgcn_mfma_f32_32x32x16_bf16(qhB.s, bhB.s, accB, 0, 0, 0);
            accA = __builtin_amdgcn_mfma_f32_32x32x16_bf16(qlA.s, bhA.s, accA, 0, 0, 0);
            accB = __builtin_amdgcn_mfma_f32_32x32x16_bf16(qlB.s, bhB.s, accB, 0, 0, 0);
            accA = __builtin_amdgcn_mfma_f32_32x32x16_bf16(qhA.s, blA.s, accA, 0, 0, 0);
            accB = __builtin_amdgcn_mfma_f32_32x32x16_bf16(qhB.s, blB.s, accB, 0, 0, 0);
        }
        float16 acc;
        #pragma unroll
        for (int r = 0; r < 16; ++r) acc[r] = accA[r] + accB[r];

        // V fragment preload: issued here so softmax hides the L2 latency
        int4 vb[8];
        #pragma unroll
        for (int u = 0; u < 8; ++u)
            vb[u] = *(const int4*)(vtH + ((size_t)(kt * 8 + u)) * 512 + ln * 8);

        // causal mask: only the diagonal tile (owned by wave g%4)
        if (kt == g) {
            #pragma unroll
            for (int r = 0; r < 16; ++r)
                if (m > 4 * hf + (r & 3) + 8 * (r >> 2)) acc[r] = NEG_BIG;
        }

        // ---- defer-max online softmax: full reduce+rescale only when needed ----
        float tm = acc[0];
        #pragma unroll
        for (int r = 1; r < 16; ++r) tm = fmaxf(tm, acc[r]);
        if (__any(tm > mrun + DEFER_THR)) {            // wave-uniform trigger
            float tw = tm;
            #pragma unroll
            for (int off = 32; off > 0; off >>= 1)
                tw = fmaxf(tw, __shfl_xor(tw, off, 64));
            const float mnew  = fmaxf(mrun, tw);
            const float alpha = __expf(mrun - mnew);   // first tile: 0
            #pragma unroll
            for (int r = 0; r < 16; ++r) {
                Oa[0][r] *= alpha; Oa[1][r] *= alpha;
                Oa[2][r] *= alpha; Oa[3][r] *= alpha;
                ls[r]    *= alpha;
            }
            mrun = mnew;
        }
        #pragma unroll
        for (int r = 0; r < 16; ++r) {
            const float p = __expf(acc[r] - mrun);     // bounded by e^8; masked -> 0
            ls[r] += p;
            Pl[w][(r & 3) + 8 * (r >> 2) + 4 * hf][m] = bf16_rne(p);
        }
        // no barrier: Pl slab is wave-private; same-wave DS ops are ordered

        // ---- PV (verified math) ----
        #pragma unroll
        for (int ks2 = 0; ks2 < 2; ++ks2) {
            union { int2 d[2]; short8 s; } up;
            const int pe = ks2 * 16 + hf * 8;
            up.d[0] = *(const int2*)&Pl[w][m][pe];
            up.d[1] = *(const int2*)&Pl[w][m][pe + 4];
            #pragma unroll
            for (int nt = 0; nt < 4; ++nt) {
                union { int4 i4; short8 s; } uv;
                uv.i4 = vb[nt * 2 + ks2];
                Oa[nt] = __builtin_amdgcn_mfma_f32_32x32x16_bf16(up.s, uv.s, Oa[nt], 0, 0, 0);
            }
        }
    }

    // ---- per-wave l reduce over the 32 key columns ----
    #pragma unroll
    for (int r = 0; r < 16; ++r) {
        float s = ls[r];
        #pragma unroll
        for (int off = 16; off > 0; off >>= 1)
            s += __shfl_xor(s, off, 64);
        ls[r] = s;
    }
    if (m == 0) {
        #pragma unroll
        for (int r = 0; r < 16; ++r)
            Lw[w][4 * hf + (r & 3) + 8 * (r >> 2)] = ls[r];
    }
    if (ln == 0) Mw[w] = mrun;                         // idle wave (w>g): NEG_BIG
    __syncthreads();                                   // qf dead from here; oc alive

    // ---- flash-decoding combine across the 4 split-K waves, 32-dim chunks ----
    const int crow = t >> 3, c0 = (t & 7) * 4;
    const float M = fmaxf(fmaxf(Mw[0], Mw[1]), fmaxf(Mw[2], Mw[3]));
    float ee[4];
    #pragma unroll
    for (int u = 0; u < 4; ++u) ee[u] = __expf(Mw[u] - M);  // idle wave -> 0
    const float L = ee[0] * Lw[0][crow] + ee[1] * Lw[1][crow]
                  + ee[2] * Lw[2][crow] + ee[3] * Lw[3][crow];
    const float inv = 1.f / L;
    float* op = out + ((size_t)(h * TT + growb + crow)) * DD;

    #pragma unroll
    for (int nt = 0; nt < 4; ++nt) {
        __syncthreads();                               // OC free for this chunk
        #pragma unroll
        for (int r = 0; r < 16; ++r)
            U.oc[w][4 * hf + (r & 3) + 8 * (r >> 2)][m] = Oa[nt][r];
        __syncthreads();                               // chunk visible
        float4 s4 = {0.f, 0.f, 0.f, 0.f};
        #pragma unroll
        for (int u = 0; u < 4; ++u) {
            const float4 ov = *(const float4*)&U.oc[u][crow][c0];
            s4.x += ee[u] * ov.x; s4.y += ee[u] * ov.y;
            s4.z += ee[u] * ov.z; s4.w += ee[u] * ov.w;
        }
        s4.x *= inv; s4.y *= inv; s4.z *= inv; s4.w *= inv;
        *(float4*)(op + nt * 32 + c0) = s4;
    }
}

extern "C" void kernel_launch(void* const* d_in, const int* in_sizes, int n_in,
                              void* d_out, int out_size, void* d_ws, size_t ws_size,
                              hipStream_t stream) {
    const float* q = (const float*)d_in[0];
    const float* k = (const float*)d_in[1];
    const float* v = (const float*)d_in[2];
    float* out = (float*)d_out;

    short* khi = (short*)d_ws;
    short* klo = khi + (size_t)HH * HEAD_FRAG_SHORTS;
    short* vt  = klo + (size_t)HH * HEAD_FRAG_SHORTS;

    prep_kernel<<<dim3(HH, NKT), dim3(256), 0, stream>>>(k, v, khi, klo, vt);
    attn_kernel<<<dim3(HH, NKT), dim3(256), 0, stream>>>(q, khi, klo, vt, out);
}

// Round 16
// 178.461 us; speedup vs baseline: 1.0651x; 1.0230x over previous
//
#include <hip/hip_runtime.h>

#define HH 8
#define TT 4096
#define DD 128
#define NKT 128              // 32-key tiles per head
#define PS 36                // P row stride in shorts (72 B rows)
#define NEG_BIG (-3.0e38f)
#define DEFER_THR 8.0f       // defer-max threshold: P bounded by e^8

// ws (shorts): Khi[8.4MB] | Klo[8.4MB] | Vt[8.4MB]
#define HEAD_FRAG_SHORTS ((size_t)NKT * 8 * 512)

typedef __attribute__((ext_vector_type(8)))  short short8;
typedef __attribute__((ext_vector_type(16))) float float16;

__device__ __forceinline__ short bf16_rne(float x) {
    unsigned u = __float_as_uint(x);
    return (short)((u + 0x7fffu + ((u >> 16) & 1u)) >> 16);
}
__device__ __forceinline__ float bf16_f(short s) {
    return __uint_as_float(((unsigned)(unsigned short)s) << 16);
}

// ---------------- prep v2: fp32 K,V -> bf16 hi/lo fragments (R13 verified) ----------------
__global__ __launch_bounds__(256) void prep_kernel(
    const float* __restrict__ k, const float* __restrict__ v,
    short* __restrict__ khi, short* __restrict__ klo, short* __restrict__ vt)
{
    const int h = blockIdx.x, kt = blockIdx.y, t = threadIdx.x;
    __shared__ float Ks[32][132];
    __shared__ float Vs[32][132];

    #pragma unroll
    for (int it = 0; it < 4; ++it) {               // stage K and V tiles, coalesced
        const int f = t + it * 256, j = f >> 5, c = f & 31;
        const size_t rowoff = ((size_t)(h * TT + kt * 32 + j)) * DD + c * 4;
        *(float4*)&Ks[j][c * 4] = *(const float4*)(k + rowoff);
        *(float4*)&Vs[j][c * 4] = *(const float4*)(v + rowoff);
    }
    __syncthreads();

    // K fragments: B[n=key m][k-dim = ks*16 + hf*8 + e]
    #pragma unroll
    for (int it = 0; it < 2; ++it) {
        const int idx = t + it * 256;
        const int ks = idx >> 6, ln = idx & 63, m = ln & 31, hf = ln >> 5;
        const float4 a = *(const float4*)&Ks[m][ks * 16 + hf * 8];
        const float4 b = *(const float4*)&Ks[m][ks * 16 + hf * 8 + 4];
        const float f8[8] = {a.x, a.y, a.z, a.w, b.x, b.y, b.z, b.w};
        short8 hi8, lo8;
        #pragma unroll
        for (int e = 0; e < 8; ++e) {
            const short hi_ = bf16_rne(f8[e]);
            hi8[e] = hi_;
            lo8[e] = bf16_rne(f8[e] - bf16_f(hi_));
        }
        const size_t off = ((size_t)((h * NKT + kt) * 8 + ks)) * 512 + ln * 8;
        *(short8*)(khi + off) = hi8;
        *(short8*)(klo + off) = lo8;
    }

    // V fragments: B[n=dim nt*32+m][k-key = ks2*16 + hf*8 + e]
    #pragma unroll
    for (int it = 0; it < 2; ++it) {
        const int idx = t + it * 256;
        const int nt = idx >> 7, ks2 = (idx >> 6) & 1, ln = idx & 63;
        const int m = ln & 31, hf = ln >> 5, n = nt * 32 + m;
        short8 o;
        #pragma unroll
        for (int e = 0; e < 8; ++e)
            o[e] = bf16_rne(Vs[ks2 * 16 + hf * 8 + e][n]);
        *(short8*)(vt + ((size_t)(((h * NKT + kt) * 4 + nt) * 2 + ks2)) * 512 + ln * 8) = o;
    }
}

// ------- attention: PAIR-BALANCED grid, R8-verbatim inner math -------
// Grid 8x64; block (h,y) computes row-tile g=127-y then g=y: uniform 129
// tiles/block, 512 blocks = exactly 2 blocks/CU, all resident from t=0,
// ZERO triangular tail (the old 8x128 big-first grid drains through 512
// backfill blocks). Inner loop / softmax / combine identical to R8
// (103.6us verified) -> output bit-identical, absmax must stay 0.03125.
// This isolates the imbalance question R14/15's failed fusion left open.
__global__ __launch_bounds__(256, 2) void attn_kernel(
    const float* __restrict__ q,
    const short* __restrict__ khi, const short* __restrict__ klo,
    const short* __restrict__ vt, float* __restrict__ out)
{
    const int h = blockIdx.x;                          // head -> XCD L2 pinning
    const int y = blockIdx.y;                          // pair id 0..63
    const int t = threadIdx.x, w = t >> 6, ln = t & 63, m = ln & 31, hf = ln >> 5;

    // qf lifetime: staging + kt loop. oc lifetime: combine. Union + barriers.
    __shared__ union {
        short qf[2][16][32][8];                        // 16 KB [hi/lo][ks*2+hf][m][e]
        float oc[4][32][36];                           // 18.4 KB combine chunks
    } U;
    __shared__ short Pl[4][32][PS];                    // wave-private P slabs (9.2 KB)
    __shared__ float Lw[4][32];
    __shared__ float Mw[4];

    const short* khiH = khi + (size_t)h * HEAD_FRAG_SHORTS;
    const short* kloH = klo + (size_t)h * HEAD_FRAG_SHORTS;
    const short* vtH  = vt  + (size_t)h * HEAD_FRAG_SHORTS;

    #pragma unroll 1
    for (int phase = 0; phase < 2; ++phase) {
        const int g = phase ? y : (NKT - 1 - y);       // big tile first
        const int growb = g * 32;
        __syncthreads();                               // prev phase's oc reads done

        // ---- stage Q (32 rows) as bf16 hi/lo A-fragments into LDS ----
        #pragma unroll
        for (int it = 0; it < 2; ++it) {
            const int idx = t + it * 256;              // 512 fragments
            const int ks = idx >> 6, l2 = idx & 63, mm = l2 & 31, hh = l2 >> 5;
            const float* src = q + ((size_t)(h * TT + growb + mm)) * DD + ks * 16 + hh * 8;
            const float4 a = *(const float4*)src;
            const float4 b = *(const float4*)(src + 4);
            const float f8[8] = {a.x, a.y, a.z, a.w, b.x, b.y, b.z, b.w};
            short8 hi8, lo8;
            #pragma unroll
            for (int e = 0; e < 8; ++e) {
                const short hi_ = bf16_rne(f8[e]);
                hi8[e] = hi_;
                lo8[e] = bf16_rne(f8[e] - bf16_f(hi_));
            }
            *(short8*)&U.qf[0][ks * 2 + hh][mm][0] = hi8;
            *(short8*)&U.qf[1][ks * 2 + hh][mm][0] = lo8;
        }
        __syncthreads();

        float16 Oa[4];
        float ls[16];
        #pragma unroll
        for (int nt = 0; nt < 4; ++nt)
            #pragma unroll
            for (int r = 0; r < 16; ++r) Oa[nt][r] = 0.f;
        #pragma unroll
        for (int r = 0; r < 16; ++r) ls[r] = 0.f;
        float mrun = NEG_BIG;

        int qoff = (hf * 32 + m) * 16;

        #pragma unroll 1
        for (int kt = w; kt <= g; kt += 4) {           // split-K: wave w owns kt≡w (mod 4)
            asm volatile("" : "+v"(qoff));             // defeat loop-invariance
            const char* qb0 = (const char*)&U.qf[0][0][0][0] + qoff;

            // ---- QK^T: 8 k-steps x 3 split-MFMAs, TWO independent acc chains ----
            float16 accA, accB;
            #pragma unroll
            for (int r = 0; r < 16; ++r) { accA[r] = 0.f; accB[r] = 0.f; }
            #pragma unroll
            for (int ks = 0; ks < 8; ks += 2) {
                union { int4 i4; short8 s; } bhA, blA, qhA, qlA, bhB, blB, qhB, qlB;
                const size_t foA = ((size_t)(kt * 8 + ks)) * 512 + ln * 8;
                const size_t foB = ((size_t)(kt * 8 + ks + 1)) * 512 + ln * 8;
                bhA.i4 = *(const int4*)(khiH + foA);
                bhB.i4 = *(const int4*)(khiH + foB);
                blA.i4 = *(const int4*)(kloH + foA);
                blB.i4 = *(const int4*)(kloH + foB);
                qhA.i4 = *(const int4*)(qb0 + ks * 1024);
                qhB.i4 = *(const int4*)(qb0 + (ks + 1) * 1024);
                qlA.i4 = *(const int4*)(qb0 + 8192 + ks * 1024);
                qlB.i4 = *(const int4*)(qb0 + 8192 + (ks + 1) * 1024);
                accA = __builtin_amdgcn_mfma_f32_32x32x16_bf16(qhA.s, bhA.s, accA, 0, 0, 0);
                accB = __builtin_amdgcn_mfma_f32_32x32x16_bf16(qhB.s, bhB.s, accB, 0, 0, 0);
                accA = __builtin_amdgcn_mfma_f32_32x32x16_bf16(qlA.s, bhA.s, accA, 0, 0, 0);
                accB = __builtin_amdgcn_mfma_f32_32x32x16_bf16(qlB.s, bhB.s, accB, 0, 0, 0);
                accA = __builtin_amdgcn_mfma_f32_32x32x16_bf16(qhA.s, blA.s, accA, 0, 0, 0);
                accB = __builtin_amdgcn_mfma_f32_32x32x16_bf16(qhB.s, blB.s, accB, 0, 0, 0);
            }
            float16 acc;
            #pragma unroll
            for (int r = 0; r < 16; ++r) acc[r] = accA[r] + accB[r];

            // V fragment preload: issued here so softmax hides the L2 latency
            int4 vb[8];
            #pragma unroll
            for (int u = 0; u < 8; ++u)
                vb[u] = *(const int4*)(vtH + ((size_t)(kt * 8 + u)) * 512 + ln * 8);

            // causal mask: only the diagonal tile (owned by wave g%4)
            if (kt == g) {
                #pragma unroll
                for (int r = 0; r < 16; ++r)
                    if (m > 4 * hf + (r & 3) + 8 * (r >> 2)) acc[r] = NEG_BIG;
            }

            // ---- defer-max online softmax ----
            float tm = acc[0];
            #pragma unroll
            for (int r = 1; r < 16; ++r) tm = fmaxf(tm, acc[r]);
            if (__any(tm > mrun + DEFER_THR)) {        // wave-uniform trigger
                float tw = tm;
                #pragma unroll
                for (int off = 32; off > 0; off >>= 1)
                    tw = fmaxf(tw, __shfl_xor(tw, off, 64));
                const float mnew  = fmaxf(mrun, tw);
                const float alpha = __expf(mrun - mnew);
                #pragma unroll
                for (int r = 0; r < 16; ++r) {
                    Oa[0][r] *= alpha; Oa[1][r] *= alpha;
                    Oa[2][r] *= alpha; Oa[3][r] *= alpha;
                    ls[r]    *= alpha;
                }
                mrun = mnew;
            }
            #pragma unroll
            for (int r = 0; r < 16; ++r) {
                const float p = __expf(acc[r] - mrun); // bounded by e^8; masked -> 0
                ls[r] += p;
                Pl[w][(r & 3) + 8 * (r >> 2) + 4 * hf][m] = bf16_rne(p);
            }
            // no barrier: Pl slab is wave-private; same-wave DS ops are ordered

            // ---- PV ----
            #pragma unroll
            for (int ks2 = 0; ks2 < 2; ++ks2) {
                union { int2 d[2]; short8 s; } up;
                const int pe = ks2 * 16 + hf * 8;
                up.d[0] = *(const int2*)&Pl[w][m][pe];
                up.d[1] = *(const int2*)&Pl[w][m][pe + 4];
                #pragma unroll
                for (int nt = 0; nt < 4; ++nt) {
                    union { int4 i4; short8 s; } uv;
                    uv.i4 = vb[nt * 2 + ks2];
                    Oa[nt] = __builtin_amdgcn_mfma_f32_32x32x16_bf16(up.s, uv.s, Oa[nt], 0, 0, 0);
                }
            }
        }

        // ---- per-wave l reduce over the 32 key columns ----
        #pragma unroll
        for (int r = 0; r < 16; ++r) {
            float s = ls[r];
            #pragma unroll
            for (int off = 16; off > 0; off >>= 1)
                s += __shfl_xor(s, off, 64);
            ls[r] = s;
        }
        if (m == 0) {
            #pragma unroll
            for (int r = 0; r < 16; ++r)
                Lw[w][4 * hf + (r & 3) + 8 * (r >> 2)] = ls[r];
        }
        if (ln == 0) Mw[w] = mrun;                     // idle wave (w>g): NEG_BIG
        __syncthreads();                               // qf dead from here; oc alive

        // ---- flash-decoding combine across the 4 split-K waves ----
        const int crow = t >> 3, c0 = (t & 7) * 4;
        const float M = fmaxf(fmaxf(Mw[0], Mw[1]), fmaxf(Mw[2], Mw[3]));
        float ee[4];
        #pragma unroll
        for (int u = 0; u < 4; ++u) ee[u] = __expf(Mw[u] - M);  // idle wave -> 0
        const float L = ee[0] * Lw[0][crow] + ee[1] * Lw[1][crow]
                      + ee[2] * Lw[2][crow] + ee[3] * Lw[3][crow];
        const float inv = 1.f / L;
        float* op = out + ((size_t)(h * TT + growb + crow)) * DD;

        #pragma unroll
        for (int nt = 0; nt < 4; ++nt) {
            __syncthreads();                           // OC free for this chunk
            #pragma unroll
            for (int r = 0; r < 16; ++r)
                U.oc[w][4 * hf + (r & 3) + 8 * (r >> 2)][m] = Oa[nt][r];
            __syncthreads();                           // chunk visible
            float4 s4 = {0.f, 0.f, 0.f, 0.f};
            #pragma unroll
            for (int u = 0; u < 4; ++u) {
                const float4 ov = *(const float4*)&U.oc[u][crow][c0];
                s4.x += ee[u] * ov.x; s4.y += ee[u] * ov.y;
                s4.z += ee[u] * ov.z; s4.w += ee[u] * ov.w;
            }
            s4.x *= inv; s4.y *= inv; s4.z *= inv; s4.w *= inv;
            *(float4*)(op + nt * 32 + c0) = s4;
        }
    }
}

extern "C" void kernel_launch(void* const* d_in, const int* in_sizes, int n_in,
                              void* d_out, int out_size, void* d_ws, size_t ws_size,
                              hipStream_t stream) {
    const float* q = (const float*)d_in[0];
    const float* k = (const float*)d_in[1];
    const float* v = (const float*)d_in[2];
    float* out = (float*)d_out;

    short* khi = (short*)d_ws;
    short* klo = khi + (size_t)HH * HEAD_FRAG_SHORTS;
    short* vt  = klo + (size_t)HH * HEAD_FRAG_SHORTS;

    prep_kernel<<<dim3(HH, NKT), dim3(256), 0, stream>>>(k, v, khi, klo, vt);
    attn_kernel<<<dim3(HH, 64), dim3(256), 0, stream>>>(q, khi, klo, vt, out);
}